// Round 1
// baseline (2903.628 us; speedup 1.0000x reference)
//
#include <hip/hip_runtime.h>

#define D 128

// ---------------- degree histogram ----------------
__global__ __launch_bounds__(256) void deg_kernel(const int* __restrict__ src,
        const int* __restrict__ dst, int* __restrict__ deg, int E, int N) {
    int e = blockIdx.x * 256 + threadIdx.x;
    if (e < E) {
        atomicAdd(&deg[src[e]], 1);       // out-degree
        atomicAdd(&deg[N + dst[e]], 1);   // in-degree
    }
}

// ---------------- fused LayerNorm + (h*norm_out) @ W ----------------
// One block = 32 rows. W (128x128 f32, 64KB) + h^T (128x32, 16KB) in LDS.
__global__ __launch_bounds__(256) void ln_gemm_kernel(const float* __restrict__ feat,
        const float* __restrict__ W, const float* __restrict__ a2, const float* __restrict__ b2,
        const int* __restrict__ deg_out, float* __restrict__ hw, int N) {
    __shared__ float Ws[D * D];      // row-major [k][c]
    __shared__ float hs[D][32];      // transposed: [k][row]

    const int t = threadIdx.x;

    // stage W: 4096 float4 / 256 threads = 16 each
    #pragma unroll
    for (int i = 0; i < 16; ++i) {
        int idx = (i * 256 + t) * 4;
        *(float4*)&Ws[idx] = *(const float4*)&W[idx];
    }

    // ---- LayerNorm phase: 8 lanes per row, 16 elems per lane ----
    const int r = t >> 3;        // row in tile 0..31
    const int sub = t & 7;       // 8-lane group
    const int grow = blockIdx.x * 32 + r;
    const bool valid = grow < N;

    float4 v[4];
    float sum = 0.f, sumsq = 0.f;
    if (valid) {
        const float4* fr = (const float4*)(feat + (size_t)grow * D + sub * 16);
        #pragma unroll
        for (int i = 0; i < 4; ++i) {
            v[i] = fr[i];
            sum   += v[i].x + v[i].y + v[i].z + v[i].w;
            sumsq += v[i].x * v[i].x + v[i].y * v[i].y + v[i].z * v[i].z + v[i].w * v[i].w;
        }
    }
    #pragma unroll
    for (int m = 1; m < 8; m <<= 1) {
        sum   += __shfl_xor(sum, m);
        sumsq += __shfl_xor(sumsq, m);
    }

    if (valid) {
        float mean = sum * (1.f / 128.f);
        float var  = fmaxf((sumsq - 128.f * mean * mean) * (1.f / 127.f), 0.f);
        float inv  = 1.f / (sqrtf(var) + 1e-6f);                    // eps on std (torch)
        float norm = rsqrtf(fmaxf((float)deg_out[grow], 1.f));      // norm_out
        float sa   = inv * norm;
        #pragma unroll
        for (int i = 0; i < 4; ++i) {
            int k = sub * 16 + i * 4;
            hs[k + 0][r] = a2[k + 0] * (v[i].x - mean) * sa + b2[k + 0] * norm;
            hs[k + 1][r] = a2[k + 1] * (v[i].y - mean) * sa + b2[k + 1] * norm;
            hs[k + 2][r] = a2[k + 2] * (v[i].z - mean) * sa + b2[k + 2] * norm;
            hs[k + 3][r] = a2[k + 3] * (v[i].w - mean) * sa + b2[k + 3] * norm;
        }
    } else {
        #pragma unroll
        for (int i = 0; i < 16; ++i) hs[sub * 16 + i][r] = 0.f;
    }

    __syncthreads();

    // ---- GEMM phase: thread computes 4 rows x 4 cols ----
    const int tx = t & 31;   // col group: cols tx*4..tx*4+3
    const int ty = t >> 5;   // row group: rows ty*4..ty*4+3
    float acc[4][4];
    #pragma unroll
    for (int i = 0; i < 4; ++i)
        #pragma unroll
        for (int j = 0; j < 4; ++j) acc[i][j] = 0.f;

    #pragma unroll 4
    for (int k = 0; k < D; ++k) {
        float4 hv = *(const float4*)&hs[k][ty * 4];
        float4 wv = *(const float4*)&Ws[k * D + tx * 4];
        float ha[4] = {hv.x, hv.y, hv.z, hv.w};
        float wa[4] = {wv.x, wv.y, wv.z, wv.w};
        #pragma unroll
        for (int i = 0; i < 4; ++i)
            #pragma unroll
            for (int j = 0; j < 4; ++j)
                acc[i][j] = fmaf(ha[i], wa[j], acc[i][j]);
    }

    #pragma unroll
    for (int i = 0; i < 4; ++i) {
        int gr = blockIdx.x * 32 + ty * 4 + i;
        if (gr < N) {
            float4 o = make_float4(acc[i][0], acc[i][1], acc[i][2], acc[i][3]);
            *(float4*)&hw[(size_t)gr * D + tx * 4] = o;
        }
    }
}

// ---------------- edge scatter-add: agg[dst] += hw[src] ----------------
// 32 lanes per edge, 4 floats per lane.
__global__ __launch_bounds__(256) void scatter_kernel(const int* __restrict__ src,
        const int* __restrict__ dst, const float* __restrict__ hw,
        float* __restrict__ agg, int E) {
    long tid = (long)blockIdx.x * 256 + threadIdx.x;
    int e    = (int)(tid >> 5);
    int lane = (int)(tid & 31);
    if (e < E) {
        int s = src[e], d = dst[e];
        float4 v = *(const float4*)&hw[(size_t)s * D + lane * 4];
        float* ap = agg + (size_t)d * D + lane * 4;
        unsafeAtomicAdd(ap + 0, v.x);
        unsafeAtomicAdd(ap + 1, v.y);
        unsafeAtomicAdd(ap + 2, v.z);
        unsafeAtomicAdd(ap + 3, v.w);
    }
}

// ---------------- out = relu(agg * norm_in + b) + feat ----------------
__global__ __launch_bounds__(256) void finalize_kernel(const float* __restrict__ feat,
        const float* __restrict__ b, const int* __restrict__ deg_in,
        float* __restrict__ out, long n4) {
    long i4 = (long)blockIdx.x * 256 + threadIdx.x;
    if (i4 < n4) {
        long row = i4 >> 5;
        int  c4  = (int)(i4 & 31);
        float ni = rsqrtf(fmaxf((float)deg_in[row], 1.f));
        float4 a  = *(const float4*)(out + i4 * 4);
        float4 f  = *(const float4*)(feat + i4 * 4);
        float4 bb = *(const float4*)(b + (size_t)c4 * 4);
        float4 o;
        o.x = fmaxf(fmaf(a.x, ni, bb.x), 0.f) + f.x;
        o.y = fmaxf(fmaf(a.y, ni, bb.y), 0.f) + f.y;
        o.z = fmaxf(fmaf(a.z, ni, bb.z), 0.f) + f.z;
        o.w = fmaxf(fmaf(a.w, ni, bb.w), 0.f) + f.w;
        *(float4*)(out + i4 * 4) = o;
    }
}

extern "C" void kernel_launch(void* const* d_in, const int* in_sizes, int n_in,
                              void* d_out, int out_size, void* d_ws, size_t ws_size,
                              hipStream_t stream) {
    const float* feat = (const float*)d_in[0];
    const int*   src  = (const int*)d_in[1];
    const int*   dst  = (const int*)d_in[2];
    const float* W    = (const float*)d_in[3];
    const float* b    = (const float*)d_in[4];
    const float* a2   = (const float*)d_in[5];
    const float* b2   = (const float*)d_in[6];

    const int N = in_sizes[0] / D;
    const int E = in_sizes[1];

    float* out = (float*)d_out;
    // ws layout: hw [N*D f32] | deg_out [N i32] | deg_in [N i32]
    float* hw  = (float*)d_ws;
    int*   deg = (int*)((char*)d_ws + (size_t)N * D * sizeof(float));

    // zero degree counters and the agg accumulator (d_out)
    hipMemsetAsync(deg, 0, (size_t)2 * N * sizeof(int), stream);
    hipMemsetAsync(out, 0, (size_t)N * D * sizeof(float), stream);

    deg_kernel<<<(E + 255) / 256, 256, 0, stream>>>(src, dst, deg, E, N);

    ln_gemm_kernel<<<(N + 31) / 32, 256, 0, stream>>>(feat, W, a2, b2, deg, hw, N);

    long sth = (long)E * 32;
    scatter_kernel<<<(int)((sth + 255) / 256), 256, 0, stream>>>(src, dst, hw, out, E);

    long n4 = (long)N * (D / 4);
    finalize_kernel<<<(int)((n4 + 255) / 256), 256, 0, stream>>>(feat, b, deg + N, out, n4);
}

// Round 2
// 419.637 us; speedup vs baseline: 6.9194x; 6.9194x over previous
//
#include <hip/hip_runtime.h>

#define D 128

// ---------------- degree histogram ----------------
__global__ __launch_bounds__(256) void deg_kernel(const int* __restrict__ src,
        const int* __restrict__ dst, int* __restrict__ deg, int E, int N) {
    int e = blockIdx.x * 256 + threadIdx.x;
    if (e < E) {
        atomicAdd(&deg[src[e]], 1);       // out-degree
        atomicAdd(&deg[N + dst[e]], 1);   // in-degree
    }
}

// ---------------- exclusive scan of in-degree -> row_start ----------------
// pass 1: per-block exclusive scan + block sums
__global__ __launch_bounds__(256) void scan1_kernel(const int* __restrict__ deg_in,
        int* __restrict__ row_start, int* __restrict__ bsum, int N) {
    __shared__ int s[256];
    int t = threadIdx.x;
    int i = blockIdx.x * 256 + t;
    int v = (i < N) ? deg_in[i] : 0;
    s[t] = v;
    __syncthreads();
    #pragma unroll
    for (int off = 1; off < 256; off <<= 1) {
        int x = (t >= off) ? s[t - off] : 0;
        __syncthreads();
        s[t] += x;
        __syncthreads();
    }
    if (i < N) row_start[i] = s[t] - v;          // exclusive
    if (t == 255) bsum[blockIdx.x] = s[255];     // block total
}

// pass 2: scan the block sums (single block, supports up to 1024 blocks)
__global__ __launch_bounds__(1024) void scan2_kernel(int* __restrict__ bsum, int nb) {
    __shared__ int s[1024];
    int t = threadIdx.x;
    int v = (t < nb) ? bsum[t] : 0;
    s[t] = v;
    __syncthreads();
    #pragma unroll
    for (int off = 1; off < 1024; off <<= 1) {
        int x = (t >= off) ? s[t - off] : 0;
        __syncthreads();
        s[t] += x;
        __syncthreads();
    }
    if (t < nb) bsum[t] = s[t] - v;              // exclusive
}

// pass 3: add block offsets; append row_start[N] = E
__global__ __launch_bounds__(256) void scan3_kernel(int* __restrict__ row_start,
        const int* __restrict__ bsum, int N, int E) {
    int i = blockIdx.x * 256 + threadIdx.x;
    if (i < N) row_start[i] += bsum[blockIdx.x];
    if (i == 0) row_start[N] = E;
}

// ---------------- bin edges by dst: csr_src[row_start[d] + pos] = src ----------------
__global__ __launch_bounds__(256) void bin_kernel(const int* __restrict__ src,
        const int* __restrict__ dst, const int* __restrict__ row_start,
        int* __restrict__ cursor, int* __restrict__ csr_src, int E) {
    int e = blockIdx.x * 256 + threadIdx.x;
    if (e < E) {
        int d = dst[e];
        int pos = atomicAdd(&cursor[d], 1);
        csr_src[row_start[d] + pos] = src[e];
    }
}

// ---------------- fused LayerNorm + (h*norm_out) @ W ----------------
// One block = 32 rows. W (128x128 f32, 64KB) + h^T (128x32, 16KB) in LDS.
__global__ __launch_bounds__(256) void ln_gemm_kernel(const float* __restrict__ feat,
        const float* __restrict__ W, const float* __restrict__ a2, const float* __restrict__ b2,
        const int* __restrict__ deg_out, float* __restrict__ hw, int N) {
    __shared__ float Ws[D * D];      // row-major [k][c]
    __shared__ float hs[D][32];      // transposed: [k][row]

    const int t = threadIdx.x;

    #pragma unroll
    for (int i = 0; i < 16; ++i) {
        int idx = (i * 256 + t) * 4;
        *(float4*)&Ws[idx] = *(const float4*)&W[idx];
    }

    const int r = t >> 3;
    const int sub = t & 7;
    const int grow = blockIdx.x * 32 + r;
    const bool valid = grow < N;

    float4 v[4];
    float sum = 0.f, sumsq = 0.f;
    if (valid) {
        const float4* fr = (const float4*)(feat + (size_t)grow * D + sub * 16);
        #pragma unroll
        for (int i = 0; i < 4; ++i) {
            v[i] = fr[i];
            sum   += v[i].x + v[i].y + v[i].z + v[i].w;
            sumsq += v[i].x * v[i].x + v[i].y * v[i].y + v[i].z * v[i].z + v[i].w * v[i].w;
        }
    }
    #pragma unroll
    for (int m = 1; m < 8; m <<= 1) {
        sum   += __shfl_xor(sum, m);
        sumsq += __shfl_xor(sumsq, m);
    }

    if (valid) {
        float mean = sum * (1.f / 128.f);
        float var  = fmaxf((sumsq - 128.f * mean * mean) * (1.f / 127.f), 0.f);
        float inv  = 1.f / (sqrtf(var) + 1e-6f);                    // eps on std (torch)
        float norm = rsqrtf(fmaxf((float)deg_out[grow], 1.f));      // norm_out
        float sa   = inv * norm;
        #pragma unroll
        for (int i = 0; i < 4; ++i) {
            int k = sub * 16 + i * 4;
            hs[k + 0][r] = a2[k + 0] * (v[i].x - mean) * sa + b2[k + 0] * norm;
            hs[k + 1][r] = a2[k + 1] * (v[i].y - mean) * sa + b2[k + 1] * norm;
            hs[k + 2][r] = a2[k + 2] * (v[i].z - mean) * sa + b2[k + 2] * norm;
            hs[k + 3][r] = a2[k + 3] * (v[i].w - mean) * sa + b2[k + 3] * norm;
        }
    } else {
        #pragma unroll
        for (int i = 0; i < 16; ++i) hs[sub * 16 + i][r] = 0.f;
    }

    __syncthreads();

    const int tx = t & 31;
    const int ty = t >> 5;
    float acc[4][4];
    #pragma unroll
    for (int i = 0; i < 4; ++i)
        #pragma unroll
        for (int j = 0; j < 4; ++j) acc[i][j] = 0.f;

    #pragma unroll 4
    for (int k = 0; k < D; ++k) {
        float4 hv = *(const float4*)&hs[k][ty * 4];
        float4 wv = *(const float4*)&Ws[k * D + tx * 4];
        float ha[4] = {hv.x, hv.y, hv.z, hv.w};
        float wa[4] = {wv.x, wv.y, wv.z, wv.w};
        #pragma unroll
        for (int i = 0; i < 4; ++i)
            #pragma unroll
            for (int j = 0; j < 4; ++j)
                acc[i][j] = fmaf(ha[i], wa[j], acc[i][j]);
    }

    #pragma unroll
    for (int i = 0; i < 4; ++i) {
        int gr = blockIdx.x * 32 + ty * 4 + i;
        if (gr < N) {
            float4 o = make_float4(acc[i][0], acc[i][1], acc[i][2], acc[i][3]);
            *(float4*)&hw[(size_t)gr * D + tx * 4] = o;
        }
    }
}

// ---------------- gather + finalize: out = relu(sum_hw * norm_in + b) + feat ----------------
// 32 lanes per node (one float4 column slice per lane); 8 nodes per block.
__global__ __launch_bounds__(256) void gather_kernel(const float* __restrict__ hw,
        const int* __restrict__ csr_src, const int* __restrict__ row_start,
        const float* __restrict__ feat, const float* __restrict__ b,
        float* __restrict__ out, int N) {
    int t = threadIdx.x;
    int lane = t & 31;
    int n = blockIdx.x * 8 + (t >> 5);
    if (n >= N) return;

    int beg = row_start[n];
    int end = row_start[n + 1];

    float4 acc = make_float4(0.f, 0.f, 0.f, 0.f);
    int e = beg;
    // 2-way unrolled for ILP
    for (; e + 1 < end; e += 2) {
        int s0 = csr_src[e];
        int s1 = csr_src[e + 1];
        float4 v0 = *(const float4*)&hw[(size_t)s0 * D + lane * 4];
        float4 v1 = *(const float4*)&hw[(size_t)s1 * D + lane * 4];
        acc.x += v0.x + v1.x;
        acc.y += v0.y + v1.y;
        acc.z += v0.z + v1.z;
        acc.w += v0.w + v1.w;
    }
    if (e < end) {
        int s0 = csr_src[e];
        float4 v0 = *(const float4*)&hw[(size_t)s0 * D + lane * 4];
        acc.x += v0.x; acc.y += v0.y; acc.z += v0.z; acc.w += v0.w;
    }

    float ni = rsqrtf(fmaxf((float)(end - beg), 1.f));   // in-degree from CSR
    float4 bb = *(const float4*)&b[lane * 4];
    float4 f  = *(const float4*)&feat[(size_t)n * D + lane * 4];
    float4 o;
    o.x = fmaxf(fmaf(acc.x, ni, bb.x), 0.f) + f.x;
    o.y = fmaxf(fmaf(acc.y, ni, bb.y), 0.f) + f.y;
    o.z = fmaxf(fmaf(acc.z, ni, bb.z), 0.f) + f.z;
    o.w = fmaxf(fmaf(acc.w, ni, bb.w), 0.f) + f.w;
    *(float4*)&out[(size_t)n * D + lane * 4] = o;
}

extern "C" void kernel_launch(void* const* d_in, const int* in_sizes, int n_in,
                              void* d_out, int out_size, void* d_ws, size_t ws_size,
                              hipStream_t stream) {
    const float* feat = (const float*)d_in[0];
    const int*   src  = (const int*)d_in[1];
    const int*   dst  = (const int*)d_in[2];
    const float* W    = (const float*)d_in[3];
    const float* b    = (const float*)d_in[4];
    const float* a2   = (const float*)d_in[5];
    const float* b2   = (const float*)d_in[6];

    const int N = in_sizes[0] / D;
    const int E = in_sizes[1];
    const int NB = (N + 255) / 256;   // scan blocks (must be <= 1024)

    float* out = (float*)d_out;

    // ws layout:
    //   hw        [N*D f32]
    //   deg       [2N i32]  (out-deg at [0,N), in-deg at [N,2N))
    //   cursor    [N i32]
    //   row_start [N+1 i32]
    //   bsum      [1024 i32]
    //   csr_src   [E i32]
    float* hw        = (float*)d_ws;
    int*   deg       = (int*)(hw + (size_t)N * D);
    int*   cursor    = deg + (size_t)2 * N;
    int*   row_start = cursor + N;
    int*   bsum      = row_start + (N + 1);
    int*   csr_src   = bsum + 1024;

    // zero deg (2N) + cursor (N) in one memset
    hipMemsetAsync(deg, 0, (size_t)3 * N * sizeof(int), stream);

    deg_kernel<<<(E + 255) / 256, 256, 0, stream>>>(src, dst, deg, E, N);

    // exclusive scan of in-degree -> row_start
    scan1_kernel<<<NB, 256, 0, stream>>>(deg + N, row_start, bsum, N);
    scan2_kernel<<<1, 1024, 0, stream>>>(bsum, NB);
    scan3_kernel<<<NB, 256, 0, stream>>>(row_start, bsum, N, E);

    // bin edges by dst
    bin_kernel<<<(E + 255) / 256, 256, 0, stream>>>(src, dst, row_start, cursor, csr_src, E);

    // LN + GEMM (needs out-degree)
    ln_gemm_kernel<<<(N + 31) / 32, 256, 0, stream>>>(feat, W, a2, b2, deg, hw, N);

    // gather + finalize
    gather_kernel<<<(N + 7) / 8, 256, 0, stream>>>(hw, csr_src, row_start, feat, b, out, N);
}